// Round 2
// baseline (786.157 us; speedup 1.0000x reference)
//
#include <hip/hip_runtime.h>

// Haar downsample: x (8,64,512,512) f32 -> out (8,192,256,256) f32.
// o0=(a-b-c+d)/2, o1=(a-b+c-d)/2, o2=(a+b-c-d)/2 where
// a=x[2h,2w], b=x[2h,2w+1], c=x[2h+1,2w], d=x[2h+1,2w+1].
// Memory-bound: 512 MiB in + 384 MiB out => ~142 us roofline @ 6.3 TB/s.
//
// R1: one thread -> 2 output cols. Each lane loads ONE contiguous float4
// per input row (lane-stride 16B = perfectly coalesced, 1 KiB/wave/instr).
// Previous version had lane-stride 32B (half-touched cache lines per instr).

#define BC_TOTAL 512       // B*C = 8*64
#define H 512
#define W 512
#define H2 256
#define W2 256
#define IN_PLANE (H * W)        // 262144
#define OUT_PLANE (H2 * W2)     // 65536

__global__ __launch_bounds__(256) void haar_down_kernel(
    const float* __restrict__ in, float* __restrict__ out) {
    const int idx = blockIdx.x * blockDim.x + threadIdx.x;
    const int w4 = idx & 127;         // 128 float4-groups per input row
    const int h2 = (idx >> 7) & 255;  // 256 output rows
    const int bc = idx >> 15;         // 512 (b,c) planes

    const float* ib = in + (size_t)bc * IN_PLANE + ((size_t)(h2 << 1)) * W + (w4 << 2);
    const float4 r0 = *reinterpret_cast<const float4*>(ib);      // a0 b0 a1 b1
    const float4 r1 = *reinterpret_cast<const float4*>(ib + W);  // c0 d0 c1 d1

    float2 o0, o1, o2;
    {
        const float a = r0.x, b = r0.y, c = r1.x, d = r1.y;
        o0.x = (a - b - c + d) * 0.5f;
        o1.x = (a - b + c - d) * 0.5f;
        o2.x = (a + b - c - d) * 0.5f;
    }
    {
        const float a = r0.z, b = r0.w, c = r1.z, d = r1.w;
        o0.y = (a - b - c + d) * 0.5f;
        o1.y = (a - b + c - d) * 0.5f;
        o2.y = (a + b - c - d) * 0.5f;
    }

    // out[b][c][k][h2][w2]: plane stride OUT_PLANE, (b,c) stride 3*OUT_PLANE
    float* ob = out + (size_t)bc * (3 * OUT_PLANE) + ((size_t)h2 << 8) + (w4 << 1);
    *reinterpret_cast<float2*>(ob) = o0;
    *reinterpret_cast<float2*>(ob + OUT_PLANE) = o1;
    *reinterpret_cast<float2*>(ob + 2 * OUT_PLANE) = o2;
}

extern "C" void kernel_launch(void* const* d_in, const int* in_sizes, int n_in,
                              void* d_out, int out_size, void* d_ws, size_t ws_size,
                              hipStream_t stream) {
    const float* x = (const float*)d_in[0];
    float* out = (float*)d_out;
    // total threads = 512 * 256 * 128 = 16,777,216 -> 65536 blocks of 256
    const int total = BC_TOTAL * H2 * (W2 / 2);
    haar_down_kernel<<<total / 256, 256, 0, stream>>>(x, out);
}